// Round 15
// baseline (948.934 us; speedup 1.0000x reference)
//
#include <hip/hip_runtime.h>
#include <math.h>

// LightingSpeechShield — B=1024, F=257, C=32; fp32 in/out.
// R13: 600 µs (best: conv stored once, k_layer 86 µs). R14: packed-fp32 pkfma
//      REGRESSED (95 µs, VALUBusy 66->49, VGPR 60->72) — reverted.
// R15: R13 hot loops byte-identical + (a) k_reduce fused into k_conv via 64
//      atomicAdds/block (removes 4 dispatches + partials traffic), (b) k_head
//      reads rows direct from global (drops 36KB LDS staging + barrier).

#define BB 1024
#define FF 257
#define BF (BB*FF)
#define TILE 64
#define NT 5
#define NBLK (BB*NT)       // 5120
#define NLAYER 4
#define SQ 36              // qs/ks/vs row stride (16B-aligned)

__device__ __forceinline__ float gelu_exact(float x){
    return 0.5f*x*(1.0f+erff(x*0.70710678118654752f));
}
__device__ __forceinline__ float dot4(float4 a, float4 b, float acc){
    return fmaf(a.x,b.x,fmaf(a.y,b.y,fmaf(a.z,b.z,fmaf(a.w,b.w,acc))));
}

__global__ __launch_bounds__(256) void k_zero(float* __restrict__ stats){
    stats[threadIdx.x]=0.0f;   // 256 = NLAYER*64
}

// ---------------- input projection: h = x(B,F,18) @ in_w(18,32) + in_b ----------------
__global__ __launch_bounds__(256) void k_inproj(const float* __restrict__ x,
        const float* __restrict__ in_w, const float* __restrict__ in_b,
        float* __restrict__ h)
{
    __shared__ float xs[TILE*18];
    int b = blockIdx.x / NT, t = blockIdx.x % NT, t0 = t*TILE;
    int tid = threadIdx.x;
    int nv = min(TILE, FF-t0);
    for (int i=tid;i<nv*18;i+=256) xs[i]=x[(size_t)(b*FF+t0)*18+i];
    __syncthreads();
    int co=tid&31, rq=tid>>5, rbase=rq*8;
    float bias = in_b[co];
    float a0=bias,a1=bias,a2=bias,a3=bias,a4=bias,a5=bias,a6=bias,a7=bias;
    #pragma unroll
    for (int ci=0;ci<18;ci++){
        float w = in_w[ci*32+co];
        a0=fmaf(xs[(rbase+0)*18+ci],w,a0);
        a1=fmaf(xs[(rbase+1)*18+ci],w,a1);
        a2=fmaf(xs[(rbase+2)*18+ci],w,a2);
        a3=fmaf(xs[(rbase+3)*18+ci],w,a3);
        a4=fmaf(xs[(rbase+4)*18+ci],w,a4);
        a5=fmaf(xs[(rbase+5)*18+ci],w,a5);
        a6=fmaf(xs[(rbase+6)*18+ci],w,a6);
        a7=fmaf(xs[(rbase+7)*18+ci],w,a7);
    }
    size_t base=(size_t)(b*FF+t0+rbase)*32+co;
    if (rbase+0<nv) h[base+0*32]=a0;
    if (rbase+1<nv) h[base+1*32]=a1;
    if (rbase+2<nv) h[base+2*32]=a2;
    if (rbase+3<nv) h[base+3*32]=a3;
    if (rbase+4<nv) h[base+4*32]=a4;
    if (rbase+5<nv) h[base+5*32]=a5;
    if (rbase+6<nv) h[base+6*32]=a6;
    if (rbase+7<nv) h[base+7*32]=a7;
}

// sliding-window conv body: 10 broadcast b128 rows, 24 named dot4s.
#define CONV_C4_BODY(HSROW) \
    { float4 hv; \
      hv=*(const float4*)(HSROW+0*32); a0=dot4(hv,w0,a0); \
      hv=*(const float4*)(HSROW+1*32); a0=dot4(hv,w1,a0); a1=dot4(hv,w0,a1); \
      hv=*(const float4*)(HSROW+2*32); a0=dot4(hv,w2,a0); a1=dot4(hv,w1,a1); a2=dot4(hv,w0,a2); \
      hv=*(const float4*)(HSROW+3*32); a1=dot4(hv,w2,a1); a2=dot4(hv,w1,a2); a3=dot4(hv,w0,a3); \
      hv=*(const float4*)(HSROW+4*32); a2=dot4(hv,w2,a2); a3=dot4(hv,w1,a3); a4=dot4(hv,w0,a4); \
      hv=*(const float4*)(HSROW+5*32); a3=dot4(hv,w2,a3); a4=dot4(hv,w1,a4); a5=dot4(hv,w0,a5); \
      hv=*(const float4*)(HSROW+6*32); a4=dot4(hv,w2,a4); a5=dot4(hv,w1,a5); a6=dot4(hv,w0,a6); \
      hv=*(const float4*)(HSROW+7*32); a5=dot4(hv,w2,a5); a6=dot4(hv,w1,a6); a7=dot4(hv,w0,a7); \
      hv=*(const float4*)(HSROW+8*32); a6=dot4(hv,w2,a6); a7=dot4(hv,w1,a7); \
      hv=*(const float4*)(HSROW+9*32); a7=dot4(hv,w2,a7); }

// ---------------- conv -> store raw conv to `c` + fused BN stats atomics ----------------
__global__ __launch_bounds__(256) void k_conv(const float* __restrict__ h,
        const float* __restrict__ conv_w, int layer, float* __restrict__ c,
        float* __restrict__ stats)
{
    __shared__ float hs[66*32];      // rows f = t0-1 .. t0+64
    __shared__ float ps[8][32];
    __shared__ float pq[8][32];
    int b=blockIdx.x/NT, t=blockIdx.x%NT, t0=t*TILE, tid=threadIdx.x;
    for (int i4=tid;i4<66*8;i4+=256){
        int r=i4>>3, f=t0-1+r;
        float4 v=make_float4(0.f,0.f,0.f,0.f);
        if (f>=0 && f<FF) v=*(const float4*)(h+(size_t)(b*FF+f)*32+(i4&7)*4);
        *(float4*)&hs[r*32+(i4&7)*4]=v;
    }
    __syncthreads();
    int co=tid&31, rq=tid>>5, rbase=rq*8;
    const float* wl = conv_w + layer*3072 + co;   // [wi][ci][co]
    float a0=0.f,a1=0.f,a2=0.f,a3=0.f,a4=0.f,a5=0.f,a6=0.f,a7=0.f;
    #pragma unroll 1
    for (int c4=0;c4<8;c4++){
        const float* w=wl+c4*128;
        float4 w0=make_float4(w[0],   w[32],  w[64],  w[96]);
        float4 w1=make_float4(w[1024],w[1056],w[1088],w[1120]);
        float4 w2=make_float4(w[2048],w[2080],w[2112],w[2144]);
        const float* hb=&hs[rbase*32+c4*4];
        CONV_C4_BODY(hb)
    }
    size_t base=(size_t)(b*FF+t0+rbase)*32+co;
    float ssum=0.f, ssq=0.f;
    if (t0+rbase+0<FF){ ssum+=a0; ssq+=a0*a0; c[base+0*32]=a0; }
    if (t0+rbase+1<FF){ ssum+=a1; ssq+=a1*a1; c[base+1*32]=a1; }
    if (t0+rbase+2<FF){ ssum+=a2; ssq+=a2*a2; c[base+2*32]=a2; }
    if (t0+rbase+3<FF){ ssum+=a3; ssq+=a3*a3; c[base+3*32]=a3; }
    if (t0+rbase+4<FF){ ssum+=a4; ssq+=a4*a4; c[base+4*32]=a4; }
    if (t0+rbase+5<FF){ ssum+=a5; ssq+=a5*a5; c[base+5*32]=a5; }
    if (t0+rbase+6<FF){ ssum+=a6; ssq+=a6*a6; c[base+6*32]=a6; }
    if (t0+rbase+7<FF){ ssum+=a7; ssq+=a7*a7; c[base+7*32]=a7; }
    ps[rq][co]=ssum; pq[rq][co]=ssq;
    __syncthreads();
    if (tid<32){
        float s=0.f;
        #pragma unroll
        for(int q=0;q<8;q++) s+=ps[q][tid];
        atomicAdd(&stats[tid], s);
    } else if (tid<64){
        int cc=tid-32;
        float s=0.f;
        #pragma unroll
        for(int q=0;q<8;q++) s+=pq[q][cc];
        atomicAdd(&stats[32+cc], s);
    }
}

// LayerNorm-over-32-lanes + guarded store, all in registers/shuffles.
#define LN_STORE(Y,K) { \
    float s=(Y); \
    s+=__shfl_xor(s,1); s+=__shfl_xor(s,2); s+=__shfl_xor(s,4); \
    s+=__shfl_xor(s,8); s+=__shfl_xor(s,16); \
    float m=s*(1.0f/32.0f); \
    float dd=(Y)-m; float v=dd*dd; \
    v+=__shfl_xor(v,1); v+=__shfl_xor(v,2); v+=__shfl_xor(v,4); \
    v+=__shfl_xor(v,8); v+=__shfl_xor(v,16); \
    float rsd=rsqrtf(v*(1.0f/32.0f)+1e-5f); \
    if (t0+rbase+(K)<FF) hn[(size_t)(b*FF+t0+rbase+(K))*32+co]=dd*rsd*lgv+lbv; }

// ---------------- fused layer: qkv + BN/gelu(conv) + attn + proj + LN ----------------
// cv == hn: conv value (r,co) read strictly before phase E overwrites it;
// blocks own disjoint row ranges.
__global__ __launch_bounds__(256) void k_layer(const float* __restrict__ h,
        float* __restrict__ hn, const float* __restrict__ cv,
        const float* __restrict__ stats,
        const float* __restrict__ bn_g, const float* __restrict__ bn_b,
        const float* __restrict__ qkv_w, const float* __restrict__ proj_w,
        const float* __restrict__ proj_b, const float* __restrict__ ln_g,
        const float* __restrict__ ln_b, int layer)
{
    __shared__ float hs[66*32];            // rows f = t0 .. t0+65
    __shared__ float qs[66*SQ];            // becomes attn output in-place
    __shared__ float ks[66*SQ];
    __shared__ float vs[66*SQ];

    int b=blockIdx.x/NT, t=blockIdx.x%NT, t0=t*TILE, tid=threadIdx.x;
    for (int i4=tid;i4<66*8;i4+=256){
        int r=i4>>3, f=t0+r;
        float4 v=make_float4(0.f,0.f,0.f,0.f);
        if (f<FF) v=*(const float4*)(h+(size_t)(b*FF+f)*32+(i4&7)*4);
        *(float4*)&hs[r*32+(i4&7)*4]=v;
    }
    __syncthreads();

    int co=tid&31, rq=tid>>5, rbase=rq*8;
    float y0,y1,y2,y3,y4,y5,y6,y7;
    {
        float mu  = stats[co]*(1.0f/(float)BF);
        float var = stats[32+co]*(1.0f/(float)BF) - mu*mu;
        float rs  = rsqrtf(fmaxf(var,0.f)+1e-5f);
        float g   = bn_g[layer*32+co];
        float scv = g*rs;
        float shv = bn_b[layer*32+co] - mu*g*rs;
        size_t base=(size_t)(b*FF+t0+rbase)*32+co;
        float c0=(t0+rbase+0<FF)?cv[base+0*32]:0.f;
        float c1=(t0+rbase+1<FF)?cv[base+1*32]:0.f;
        float c2=(t0+rbase+2<FF)?cv[base+2*32]:0.f;
        float c3=(t0+rbase+3<FF)?cv[base+3*32]:0.f;
        float c4v=(t0+rbase+4<FF)?cv[base+4*32]:0.f;
        float c5=(t0+rbase+5<FF)?cv[base+5*32]:0.f;
        float c6=(t0+rbase+6<FF)?cv[base+6*32]:0.f;
        float c7=(t0+rbase+7<FF)?cv[base+7*32]:0.f;
        y0=gelu_exact(fmaf(c0,scv,shv));
        y1=gelu_exact(fmaf(c1,scv,shv));
        y2=gelu_exact(fmaf(c2,scv,shv));
        y3=gelu_exact(fmaf(c3,scv,shv));
        y4=gelu_exact(fmaf(c4v,scv,shv));
        y5=gelu_exact(fmaf(c5,scv,shv));
        y6=gelu_exact(fmaf(c6,scv,shv));
        y7=gelu_exact(fmaf(c7,scv,shv));
    }
    {
        const float* wql = qkv_w + layer*3072 + co;
        float q0=0.f,q1=0.f,q2=0.f,q3=0.f,q4=0.f,q5=0.f,q6=0.f,q7=0.f;
        float k0=0.f,k1=0.f,k2=0.f,k3=0.f,k4=0.f,k5=0.f,k6=0.f,k7=0.f;
        float v0=0.f,v1=0.f,v2=0.f,v3=0.f,v4=0.f,v5=0.f,v6=0.f,v7=0.f;
        float ek=0.f, ev=0.f;               // tid<64: k,v for row 64+rq
        int edge = (tid<64);
        #pragma unroll 1
        for (int c4=0;c4<8;c4++){
            const float* qw=wql+c4*384;     // ci=c4*4, stride 96
            float4 wq=make_float4(qw[0],  qw[96], qw[192],qw[288]);
            float4 wk=make_float4(qw[32], qw[128],qw[224],qw[320]);
            float4 wv=make_float4(qw[64], qw[160],qw[256],qw[352]);
            const float* hb=&hs[rbase*32+c4*4];
            float4 hv;
            hv=*(const float4*)(hb+0*32); q0=dot4(hv,wq,q0); k0=dot4(hv,wk,k0); v0=dot4(hv,wv,v0);
            hv=*(const float4*)(hb+1*32); q1=dot4(hv,wq,q1); k1=dot4(hv,wk,k1); v1=dot4(hv,wv,v1);
            hv=*(const float4*)(hb+2*32); q2=dot4(hv,wq,q2); k2=dot4(hv,wk,k2); v2=dot4(hv,wv,v2);
            hv=*(const float4*)(hb+3*32); q3=dot4(hv,wq,q3); k3=dot4(hv,wk,k3); v3=dot4(hv,wv,v3);
            hv=*(const float4*)(hb+4*32); q4=dot4(hv,wq,q4); k4=dot4(hv,wk,k4); v4=dot4(hv,wv,v4);
            hv=*(const float4*)(hb+5*32); q5=dot4(hv,wq,q5); k5=dot4(hv,wk,k5); v5=dot4(hv,wv,v5);
            hv=*(const float4*)(hb+6*32); q6=dot4(hv,wq,q6); k6=dot4(hv,wk,k6); v6=dot4(hv,wv,v6);
            hv=*(const float4*)(hb+7*32); q7=dot4(hv,wq,q7); k7=dot4(hv,wk,k7); v7=dot4(hv,wv,v7);
            if (edge){
                float4 he=*(const float4*)(&hs[(64+rq)*32+c4*4]);
                ek=dot4(he,wk,ek); ev=dot4(he,wv,ev);
            }
        }
        int rb=rbase*SQ+co;
        qs[rb+0*SQ]=q0; ks[rb+0*SQ]=k0; vs[rb+0*SQ]=v0;
        qs[rb+1*SQ]=q1; ks[rb+1*SQ]=k1; vs[rb+1*SQ]=v1;
        qs[rb+2*SQ]=q2; ks[rb+2*SQ]=k2; vs[rb+2*SQ]=v2;
        qs[rb+3*SQ]=q3; ks[rb+3*SQ]=k3; vs[rb+3*SQ]=v3;
        qs[rb+4*SQ]=q4; ks[rb+4*SQ]=k4; vs[rb+4*SQ]=v4;
        qs[rb+5*SQ]=q5; ks[rb+5*SQ]=k5; vs[rb+5*SQ]=v5;
        qs[rb+6*SQ]=q6; ks[rb+6*SQ]=k6; vs[rb+6*SQ]=v6;
        qs[rb+7*SQ]=q7; ks[rb+7*SQ]=k7; vs[rb+7*SQ]=v7;
        if (edge){ ks[(64+rq)*SQ+co]=ek; vs[(64+rq)*SQ+co]=ev; }
    }
    __syncthreads();

    // ---- phase C: banded attention (qs in-place) ----
    {
        int r=tid>>2, hh=tid&3, f=t0+r;
        if (f<FF){
            int base=hh*8;
            float4 qa=*(const float4*)&qs[r*SQ+base];
            float4 qb=*(const float4*)&qs[r*SQ+base+4];
            float s0, s1=-1e30f, s2=-1e30f;
            s0=dot4(qa,*(const float4*)&ks[r*SQ+base],
               dot4(qb,*(const float4*)&ks[r*SQ+base+4],0.f))*0.35355339059327373f;
            if (f+1<FF)
                s1=dot4(qa,*(const float4*)&ks[(r+1)*SQ+base],
                   dot4(qb,*(const float4*)&ks[(r+1)*SQ+base+4],0.f))*0.35355339059327373f;
            if (f+2<FF)
                s2=dot4(qa,*(const float4*)&ks[(r+2)*SQ+base],
                   dot4(qb,*(const float4*)&ks[(r+2)*SQ+base+4],0.f))*0.35355339059327373f;
            float mx=fmaxf(s0,fmaxf(s1,s2));
            float e0=__expf(s0-mx);
            float e1=(f+1<FF)?__expf(s1-mx):0.f;
            float e2=(f+2<FF)?__expf(s2-mx):0.f;
            float inv=1.0f/(e0+e1+e2);
            float4 va=*(const float4*)&vs[r*SQ+base];
            float4 vb=*(const float4*)&vs[r*SQ+base+4];
            float4 oa=make_float4(e0*va.x,e0*va.y,e0*va.z,e0*va.w);
            float4 ob=make_float4(e0*vb.x,e0*vb.y,e0*vb.z,e0*vb.w);
            if (f+1<FF){
                va=*(const float4*)&vs[(r+1)*SQ+base];
                vb=*(const float4*)&vs[(r+1)*SQ+base+4];
                oa.x=fmaf(e1,va.x,oa.x); oa.y=fmaf(e1,va.y,oa.y);
                oa.z=fmaf(e1,va.z,oa.z); oa.w=fmaf(e1,va.w,oa.w);
                ob.x=fmaf(e1,vb.x,ob.x); ob.y=fmaf(e1,vb.y,ob.y);
                ob.z=fmaf(e1,vb.z,ob.z); ob.w=fmaf(e1,vb.w,ob.w);
            }
            if (f+2<FF){
                va=*(const float4*)&vs[(r+2)*SQ+base];
                vb=*(const float4*)&vs[(r+2)*SQ+base+4];
                oa.x=fmaf(e2,va.x,oa.x); oa.y=fmaf(e2,va.y,oa.y);
                oa.z=fmaf(e2,va.z,oa.z); oa.w=fmaf(e2,va.w,oa.w);
                ob.x=fmaf(e2,vb.x,ob.x); ob.y=fmaf(e2,vb.y,ob.y);
                ob.z=fmaf(e2,vb.z,ob.z); ob.w=fmaf(e2,vb.w,ob.w);
            }
            oa.x*=inv; oa.y*=inv; oa.z*=inv; oa.w*=inv;
            ob.x*=inv; ob.y*=inv; ob.z*=inv; ob.w*=inv;
            *(float4*)&qs[r*SQ+base]=oa;
            *(float4*)&qs[r*SQ+base+4]=ob;
        }
    }
    __syncthreads();

    // ---- phase D: proj + residual into y regs ----
    {
        const float* pwl = proj_w + layer*1024 + co;
        float pbv = proj_b[layer*32+co];
        float d0=pbv,d1=pbv,d2=pbv,d3=pbv,d4=pbv,d5=pbv,d6=pbv,d7=pbv;
        #pragma unroll 1
        for (int c4=0;c4<8;c4++){
            const float* w=pwl+c4*128;
            float4 wv=make_float4(w[0],w[32],w[64],w[96]);
            const float* qb=&qs[rbase*SQ+c4*4];
            d0=dot4(*(const float4*)(qb+0*SQ),wv,d0);
            d1=dot4(*(const float4*)(qb+1*SQ),wv,d1);
            d2=dot4(*(const float4*)(qb+2*SQ),wv,d2);
            d3=dot4(*(const float4*)(qb+3*SQ),wv,d3);
            d4=dot4(*(const float4*)(qb+4*SQ),wv,d4);
            d5=dot4(*(const float4*)(qb+5*SQ),wv,d5);
            d6=dot4(*(const float4*)(qb+6*SQ),wv,d6);
            d7=dot4(*(const float4*)(qb+7*SQ),wv,d7);
        }
        y0+=d0; y1+=d1; y2+=d2; y3+=d3; y4+=d4; y5+=d5; y6+=d6; y7+=d7;
    }

    // ---- phase E: LayerNorm via lane shuffles + fused store ----
    {
        float lgv=ln_g[layer*32+co];
        float lbv=ln_b[layer*32+co];
        LN_STORE(y0,0) LN_STORE(y1,1) LN_STORE(y2,2) LN_STORE(y3,3)
        LN_STORE(y4,4) LN_STORE(y5,5) LN_STORE(y6,6) LN_STORE(y7,7)
    }
}

// ---------------- head: sigmoid(gelu(h@h1+b1)@h2+b2) — no hs staging ----------------
__global__ __launch_bounds__(256) void k_head(const float* __restrict__ h,
        const float* __restrict__ h1_w, const float* __restrict__ h1_b,
        const float* __restrict__ h2_w, const float* __restrict__ h2_b,
        float* __restrict__ out)
{
    __shared__ float w1t[16*32];     // transposed h1_w
    int tid=threadIdx.x;
    int r0=blockIdx.x*256;           // BF == 1028*256 exactly
    for (int i=tid;i<512;i+=256) w1t[i]=h1_w[(i&31)*16+(i>>5)];
    const float* hr = h + (size_t)(r0+tid)*32;
    float4 hv0=*(const float4*)(hr+ 0);
    float4 hv1=*(const float4*)(hr+ 4);
    float4 hv2=*(const float4*)(hr+ 8);
    float4 hv3=*(const float4*)(hr+12);
    float4 hv4=*(const float4*)(hr+16);
    float4 hv5=*(const float4*)(hr+20);
    float4 hv6=*(const float4*)(hr+24);
    float4 hv7=*(const float4*)(hr+28);
    __syncthreads();
    float acc2=h2_b[0];
    #pragma unroll
    for (int j=0;j<16;j++){
        const float* wr=&w1t[j*32];
        float aj=h1_b[j];
        aj=dot4(hv0,*(const float4*)(wr+ 0),aj);
        aj=dot4(hv1,*(const float4*)(wr+ 4),aj);
        aj=dot4(hv2,*(const float4*)(wr+ 8),aj);
        aj=dot4(hv3,*(const float4*)(wr+12),aj);
        aj=dot4(hv4,*(const float4*)(wr+16),aj);
        aj=dot4(hv5,*(const float4*)(wr+20),aj);
        aj=dot4(hv6,*(const float4*)(wr+24),aj);
        aj=dot4(hv7,*(const float4*)(wr+28),aj);
        acc2=fmaf(gelu_exact(aj), h2_w[j], acc2);
    }
    out[r0+tid]=1.0f/(1.0f+__expf(-acc2));
}

extern "C" void kernel_launch(void* const* d_in, const int* in_sizes, int n_in,
                              void* d_out, int out_size, void* d_ws, size_t ws_size,
                              hipStream_t stream)
{
    const float* x     =(const float*)d_in[0];
    const float* in_w  =(const float*)d_in[1];
    const float* in_b  =(const float*)d_in[2];
    const float* conv_w=(const float*)d_in[3];
    const float* bn_g  =(const float*)d_in[4];
    const float* bn_b  =(const float*)d_in[5];
    const float* qkv_w =(const float*)d_in[6];
    const float* proj_w=(const float*)d_in[7];
    const float* proj_b=(const float*)d_in[8];
    const float* ln_g  =(const float*)d_in[9];
    const float* ln_b  =(const float*)d_in[10];
    const float* h1_w  =(const float*)d_in[11];
    const float* h1_b  =(const float*)d_in[12];
    const float* h2_w  =(const float*)d_in[13];
    const float* h2_b  =(const float*)d_in[14];

    float* bufA     = (float*)d_ws;
    float* bufB     = bufA + (size_t)BF*32;
    float* stats    = bufB + (size_t)BF*32;   // NLAYER*64 floats

    k_zero<<<1,256,0,stream>>>(stats);
    k_inproj<<<NBLK,256,0,stream>>>(x,in_w,in_b,bufA);
    for (int l=0;l<NLAYER;l++){
        float* cur = (l&1)? bufB : bufA;
        float* nxt = (l&1)? bufA : bufB;
        k_conv<<<NBLK,256,0,stream>>>(cur, conv_w, l, nxt, stats + l*64);
        k_layer<<<NBLK,256,0,stream>>>(cur, nxt, nxt, stats+l*64, bn_g, bn_b,
                                       qkv_w, proj_w, proj_b, ln_g, ln_b, l);
    }
    k_head<<<1028,256,0,stream>>>(bufA, h1_w,h1_b,h2_w,h2_b, (float*)d_out);
}